// Round 14
// baseline (481.820 us; speedup 1.0000x reference)
//
#include <hip/hip_runtime.h>
#include <hip/hip_fp16.h>
#include <cstdint>
#include <cstddef>

#define H    50
#define TT   256      // timesteps
#define BATCH 512
#define KDIM 144      // layer-0 input dim
#define ODIM 144      // FC output dim
#define NW   32       // windows
#define WS   8        // steps per window

typedef _Float16 half8  __attribute__((ext_vector_type(8)));
typedef _Float16 half4v __attribute__((ext_vector_type(4)));
typedef float    floatx4 __attribute__((ext_vector_type(4)));
typedef int      int4v  __attribute__((ext_vector_type(4)));

__device__ __forceinline__ float rcpf(float x) { return __builtin_amdgcn_rcpf(x); }
__device__ __forceinline__ float sigm(float x) { return rcpf(1.0f + __expf(-x)); }
__device__ __forceinline__ float tanhx(float x) {
    return 1.0f - 2.0f * rcpf(__expf(2.0f * x) + 1.0f);
}

// Raw barrier: orders LDS (lgkmcnt) but leaves global loads (vmcnt) in flight.
__device__ __forceinline__ void sync_lds() {
    asm volatile("s_waitcnt lgkmcnt(0)\n\ts_barrier" ::: "memory");
}
// Wave-local LDS write->read ordering (once per window after gp scatter).
__device__ __forceinline__ void wave_lds_fence() {
    asm volatile("s_waitcnt lgkmcnt(0)" ::: "memory");
}

// ---------- A-fragment builders (A layout: row m = lane&15, k = q*8 + j) ----------
// K=64 hidden rows (Whh0 / Whh1): k<50 = W[p][k], else 0.
__device__ __forceinline__ half8 make_hh(const float* __restrict__ Wt,
                                         int kkA, int gate, int q, int s) {
    const float* r0 = Wt + (size_t)(gate * H + (kkA < H ? kkA : 0)) * H;
    half8 r;
    #pragma unroll
    for (int j = 0; j < 8; ++j) {
        const int k = s * 32 + q * 8 + j;
        r[j] = (_Float16)((kkA < H && k < H) ? r0[k] : 0.0f);
    }
    return r;
}
// x-projection rows: K=160 pad; k<144 = W_ih0, k==144 = bias0 (rides 1.0 B-channel)
__device__ __forceinline__ half8 make_ax(const float* __restrict__ Wih0,
                                         const float* __restrict__ bih0,
                                         const float* __restrict__ bhh0,
                                         int kkA, int gate, int q, int s) {
    const int p = gate * H + (kkA < H ? kkA : 0);
    half8 r;
    #pragma unroll
    for (int j = 0; j < 8; ++j) {
        const int k = s * 32 + q * 8 + j;
        float v = 0.0f;
        if (kkA < H) {
            if (k < KDIM)        v = Wih0[(size_t)p * KDIM + k];
            else if (k == KDIM)  v = bih0[p] + bhh0[p];
        }
        r[j] = (_Float16)v;
    }
    return r;
}
// L1 input-projection rows (over h0 window): K=64; k<50 = W_ih1, k==50 = bias1.
__device__ __forceinline__ half8 make_p1(const float* __restrict__ Wih1,
                                         const float* __restrict__ bih1,
                                         const float* __restrict__ bhh1,
                                         int kkA, int gate, int q, int s) {
    const int p = gate * H + (kkA < H ? kkA : 0);
    half8 r;
    #pragma unroll
    for (int j = 0; j < 8; ++j) {
        const int k = s * 32 + q * 8 + j;
        float v = 0.0f;
        if (kkA < H) {
            if (k < H)           v = Wih1[(size_t)p * H + k];
            else if (k == H)     v = bih1[p] + bhh1[p];
        }
        r[j] = (_Float16)v;
    }
    return r;
}

// ---------- Fused kernel: 1 batch row / block, 4 waves, 2 blocks/CU ----------
// 512 blocks: two independent recurrent streams co-resident per CU. Their
// barriers interleave -> block A's serial-chain stalls are filled by block B's
// issue (and vice versa). Per wave: 4 A-tiles/layer (au = 16w+4tl+q), per step
// 16 hh MFMAs (a0 K64 over h0, a1 K64 over h1). Broadcast-B: all 16 C cols hold
// the row's gate quads; lane (col,q) selects quad col>>1 = (atl,aL) via 28
// cndmask. L0 x-proj and L1 input-proj batched per 8-step window (gp0/gp1).
// h0 lives only in the HW window buffer (no B0). One raw s_barrier per step.
__global__ __launch_bounds__(256, 2) void lstm_fused(
    const float* __restrict__ X,
    const float* __restrict__ Whh0, const float* __restrict__ Wih0,
    const float* __restrict__ bih0, const float* __restrict__ bhh0,
    const float* __restrict__ Wih1, const float* __restrict__ Whh1,
    const float* __restrict__ bih1, const float* __restrict__ bhh1,
    const float* __restrict__ Wfc, const float* __restrict__ bfc,
    float* __restrict__ out)
{
    const int b    = blockIdx.x;     // batch row
    const int tid  = threadIdx.x;    // 0..255
    const int lane = tid & 63;
    const int w    = tid >> 6;       // wave 0..3
    const int col  = lane & 15;      // C col
    const int q    = lane >> 4;      // 0..3

    __shared__ __align__(16) _Float16 B1[2][2][4][8];       // h1 state [buf][s][q][j]
    __shared__ __align__(16) _Float16 HW[2][2][4][8][8];    // h0 window [buf][s][q][tok][j], 1.0@k=50
    __shared__ __align__(16) _Float16 XB[2][5][4][8][8];    // x window  [buf][s][q][tok][j], 1.0@k=144
    __shared__ __align__(16) float    gp0[64 * 36];         // L0 xproj quads [u][t*4+g]
    __shared__ __align__(16) float    gp1[64 * 36];         // L1 h0proj quads
    __shared__ float h1f[52];

    // ---- inline A-prep: 44 frags/thread (4 tiles x {hh0:2, ax:5, hh1:2, p1:2}) ----
    int4v Ap[44];
    {
        const int prow = lane & 15;
        const int gate = prow & 3;
        #pragma unroll
        for (int tl = 0; tl < 4; ++tl) {
            const int kkA = 16 * w + 4 * tl + (prow >> 2);
            #pragma unroll
            for (int s = 0; s < 2; ++s) Ap[tl * 2 + s]      = __builtin_bit_cast(int4v, make_hh(Whh0, kkA, gate, q, s));
            #pragma unroll
            for (int s = 0; s < 5; ++s) Ap[8 + tl * 5 + s]  = __builtin_bit_cast(int4v, make_ax(Wih0, bih0, bhh0, kkA, gate, q, s));
            #pragma unroll
            for (int s = 0; s < 2; ++s) Ap[28 + tl * 2 + s] = __builtin_bit_cast(int4v, make_hh(Whh1, kkA, gate, q, s));
            #pragma unroll
            for (int s = 0; s < 2; ++s) Ap[36 + tl * 2 + s] = __builtin_bit_cast(int4v, make_p1(Wih1, bih1, bhh1, kkA, gate, q, s));
        }
    }
    #pragma unroll
    for (int i = 0; i < 44; ++i) asm volatile("" : "+a"(Ap[i]));

    // ---- act decode: lane (col,q) owns cell (unit au, layer aL); odd cols dup ----
    const int  c2  = col >> 1;           // quad index 0..7
    const int  atl = c2 & 3;             // tile
    const int  aL  = c2 >> 2;            // layer
    const int  au  = 16 * w + 4 * atl + q;
    const bool valid = ((col & 1) == 0);
    const bool areal = (au < H);
    float c = 0.0f;
    const float* gpb = (aL ? gp1 : gp0) + au * 36;

    // ---- x-stage decode: 288 float4/window over 256 threads (+32 extra) ----
    const int cs1 = tid / 36,         kk1 = tid % 36;
    const int cs2 = (tid + 256) / 36, kk2 = (tid + 256) % 36;   // only tid<32
    const float* xq1 = X + ((size_t)b * TT + cs1) * KDIM + kk1 * 4;
    const float* xq2 = X + ((size_t)b * TT + cs2) * KDIM + kk2 * 4;

    // ---- init: zero B1/HW/XB/gp1, set 1.0 channels, stage XB[0] (tokens 0..7) ----
    // XB zeroing is REQUIRED: K-pad slots k=145..159 are never written by the
    // x-stage; uninitialized LDS there reads as garbage f16 (possibly NaN) and
    // MFMA's 0*NaN = NaN poisons the accumulator (R13 failure).
    if (tid < 64) ((int*)B1)[tid] = 0;
    for (int i = tid; i < 512; i += 256) ((int*)HW)[i] = 0;
    for (int i = tid; i < 1280; i += 256) ((int*)XB)[i] = 0;
    for (int i = tid; i < 2304; i += 256) gp1[i] = 0.0f;
    __syncthreads();
    if (tid < 16) {
        HW[tid >> 3][1][2][tid & 7][2] = (_Float16)1.0f;   // k=50 bias1 channel (both bufs)
        XB[tid >> 3][4][2][tid & 7][0] = (_Float16)1.0f;   // k=144 bias0 channel (both bufs)
    }
    __syncthreads();
    {
        const float4 v1 = *(const float4*)xq1;
        half4v h; h[0]=(_Float16)v1.x; h[1]=(_Float16)v1.y; h[2]=(_Float16)v1.z; h[3]=(_Float16)v1.w;
        *(half4v*)&XB[0][kk1 >> 3][(kk1 >> 1) & 3][cs1][(kk1 & 1) * 4] = h;
        if (tid < 32) {
            const float4 v2 = *(const float4*)xq2;
            half4v h2; h2[0]=(_Float16)v2.x; h2[1]=(_Float16)v2.y; h2[2]=(_Float16)v2.z; h2[3]=(_Float16)v2.w;
            *(half4v*)&XB[0][kk2 >> 3][(kk2 >> 1) & 3][cs2][(kk2 & 1) * 4] = h2;
        }
    }
    __syncthreads();

    for (int W = 0; W < NW; ++W) {
        #pragma unroll
        for (int i = 0; i < 44; ++i) asm volatile("" : "+a"(Ap[i]));
        const int cb = W & 1, nb = cb ^ 1, pb = cb ^ 1;
        const bool more = (W + 1) < NW;
        // issue next-window x loads (consumed at step 3 -> latency hidden)
        float4 xv1, xv2;
        if (more) {
            xv1 = *(const float4*)(xq1 + (size_t)(W + 1) * WS * KDIM);
            if (tid < 32) xv2 = *(const float4*)(xq2 + (size_t)(W + 1) * WS * KDIM);
        }
        // ---- window top: L0 x-proj + bias0 (8 tokens; cols 8-15 dup) ----
        {
            half8 xbf[5];
            #pragma unroll
            for (int s = 0; s < 5; ++s) xbf[s] = *(const half8*)&XB[cb][s][q][col & 7][0];
            #pragma unroll
            for (int tl = 0; tl < 4; ++tl) {
                floatx4 px = (floatx4)(0.0f);
                #pragma unroll
                for (int s = 0; s < 5; ++s)
                    px = __builtin_amdgcn_mfma_f32_16x16x32_f16(__builtin_bit_cast(half8, Ap[8 + tl * 5 + s]), xbf[s], px, 0, 0, 0);
                if (col < 8)
                    *(floatx4*)&gp0[(16 * w + 4 * tl + q) * 36 + col * 4] = px;
            }
        }
        // ---- window top: L1 h0-proj + bias1 over previous window's h0 (HW[pb]) ----
        if (W > 0) {
            half8 hbf[2];
            #pragma unroll
            for (int s = 0; s < 2; ++s) hbf[s] = *(const half8*)&HW[pb][s][q][col & 7][0];
            #pragma unroll
            for (int tl = 0; tl < 4; ++tl) {
                floatx4 pw = (floatx4)(0.0f);
                #pragma unroll
                for (int s = 0; s < 2; ++s)
                    pw = __builtin_amdgcn_mfma_f32_16x16x32_f16(__builtin_bit_cast(half8, Ap[36 + tl * 2 + s]), hbf[s], pw, 0, 0, 0);
                if (col < 8)
                    *(floatx4*)&gp1[(16 * w + 4 * tl + q) * 36 + col * 4] = pw;
            }
        }
        wave_lds_fence();   // gp scatter -> same-wave act reads
        // ---- 8 serial steps: L0 at t=8W+i, L1 at t'=8(W-1)+i ----
        #pragma unroll
        for (int i = 0; i < WS; ++i) {
            const int rb = i & 1, wb = rb ^ 1;
            const int b0i = (i == 0) ? pb : cb;        // h0(t-1) lives in HW
            const int tprev = (i == 0) ? 7 : (i - 1);
            half8 bf0[2], bf1[2];
            #pragma unroll
            for (int s = 0; s < 2; ++s) {
                bf0[s] = *(const half8*)&HW[b0i][s][q][tprev][0];   // broadcast
                bf1[s] = *(const half8*)&B1[rb][s][q][0];           // broadcast
            }
            const floatx4 gx = *(const floatx4*)&gpb[i * 4];
            floatx4 a0[4], a1[4];
            #pragma unroll
            for (int tl = 0; tl < 4; ++tl) { a0[tl] = (floatx4)(0.0f); a1[tl] = (floatx4)(0.0f); }
            #pragma unroll
            for (int tl = 0; tl < 4; ++tl) {
                #pragma unroll
                for (int s = 0; s < 2; ++s) {
                    a0[tl] = __builtin_amdgcn_mfma_f32_16x16x32_f16(__builtin_bit_cast(half8, Ap[tl*2+s]),    bf0[s], a0[tl], 0, 0, 0);
                    a1[tl] = __builtin_amdgcn_mfma_f32_16x16x32_f16(__builtin_bit_cast(half8, Ap[28+tl*2+s]), bf1[s], a1[tl], 0, 0, 0);
                }
            }
            // ---- in-register 8-way quad select (28 cndmask) ----
            floatx4 g;
            #pragma unroll
            for (int gi_ = 0; gi_ < 4; ++gi_) {
                const float s01a = (c2 & 1) ? a0[1][gi_] : a0[0][gi_];
                const float s23a = (c2 & 1) ? a0[3][gi_] : a0[2][gi_];
                const float s01b = (c2 & 1) ? a1[1][gi_] : a1[0][gi_];
                const float s23b = (c2 & 1) ? a1[3][gi_] : a1[2][gi_];
                const float e0 = (c2 & 2) ? s23a : s01a;
                const float e1 = (c2 & 2) ? s23b : s01b;
                g[gi_] = (c2 & 4) ? e1 : e0;
            }
            g[0] += gx[0]; g[1] += gx[1]; g[2] += gx[2]; g[3] += gx[3];
            // ---- act: one cell per lane (L1 lags a window: dead at W==0) ----
            const float gi = sigm(g[0]), gf = sigm(g[1]);
            const float gg = tanhx(g[2]), go = sigm(g[3]);
            const bool en = (aL == 0) || (W > 0);
            const float cn = gf * c + gi * gg;
            c = en ? cn : c;
            const float hv = go * tanhx(c);
            if (valid && areal && en) {
                const _Float16 h16 = (_Float16)hv;
                if (aL == 0)
                    HW[cb][au >> 5][(au >> 3) & 3][i][au & 7] = h16;
                else
                    B1[wb][au >> 5][(au >> 3) & 3][au & 7] = h16;
            }
            // mid-window: write next-window x into XB[nb] (loads long in flight)
            if (i == 3 && more) {
                half4v h; h[0]=(_Float16)xv1.x; h[1]=(_Float16)xv1.y; h[2]=(_Float16)xv1.z; h[3]=(_Float16)xv1.w;
                *(half4v*)&XB[nb][kk1 >> 3][(kk1 >> 1) & 3][cs1][(kk1 & 1) * 4] = h;
                if (tid < 32) {
                    half4v h2; h2[0]=(_Float16)xv2.x; h2[1]=(_Float16)xv2.y; h2[2]=(_Float16)xv2.z; h2[3]=(_Float16)xv2.w;
                    *(half4v*)&XB[nb][kk2 >> 3][(kk2 >> 1) & 3][cs2][(kk2 & 1) * 4] = h2;
                }
            }
            sync_lds();         // HW[cb]/B1[wb]/XB[nb] -> next step
        }
    }
    // ---- tail window: L1 for t' = TT-8 .. TT-1 (h0 from HW[(NW-1)&1]) ----
    {
        #pragma unroll
        for (int i = 0; i < 44; ++i) asm volatile("" : "+a"(Ap[i]));
        {
            half8 hbf[2];
            #pragma unroll
            for (int s = 0; s < 2; ++s) hbf[s] = *(const half8*)&HW[(NW - 1) & 1][s][q][col & 7][0];
            #pragma unroll
            for (int tl = 0; tl < 4; ++tl) {
                floatx4 pw = (floatx4)(0.0f);
                #pragma unroll
                for (int s = 0; s < 2; ++s)
                    pw = __builtin_amdgcn_mfma_f32_16x16x32_f16(__builtin_bit_cast(half8, Ap[36 + tl * 2 + s]), hbf[s], pw, 0, 0, 0);
                if (col < 8)
                    *(floatx4*)&gp1[(16 * w + 4 * tl + q) * 36 + col * 4] = pw;
            }
        }
        wave_lds_fence();
        #pragma unroll
        for (int i = 0; i < WS; ++i) {
            const int rb = i & 1, wb = rb ^ 1;
            half8 bf1[2];
            #pragma unroll
            for (int s = 0; s < 2; ++s) bf1[s] = *(const half8*)&B1[rb][s][q][0];
            const floatx4 gx = *(const floatx4*)&gpb[i * 4];
            floatx4 a1[4];
            #pragma unroll
            for (int tl = 0; tl < 4; ++tl) {
                a1[tl] = (floatx4)(0.0f);
                #pragma unroll
                for (int s = 0; s < 2; ++s)
                    a1[tl] = __builtin_amdgcn_mfma_f32_16x16x32_f16(__builtin_bit_cast(half8, Ap[28+tl*2+s]), bf1[s], a1[tl], 0, 0, 0);
            }
            floatx4 g;
            #pragma unroll
            for (int gi_ = 0; gi_ < 4; ++gi_) {
                const float s01 = (c2 & 1) ? a1[1][gi_] : a1[0][gi_];
                const float s23 = (c2 & 1) ? a1[3][gi_] : a1[2][gi_];
                g[gi_] = (c2 & 2) ? s23 : s01;
            }
            g[0] += gx[0]; g[1] += gx[1]; g[2] += gx[2]; g[3] += gx[3];
            const float gi = sigm(g[0]), gf = sigm(g[1]);
            const float gg = tanhx(g[2]), go = sigm(g[3]);
            const bool en = (aL == 1);
            const float cn = gf * c + gi * gg;
            c = en ? cn : c;
            const float hv = go * tanhx(c);
            if (valid && en && areal) {
                B1[wb][au >> 5][(au >> 3) & 3][au & 7] = (_Float16)hv;
                if (i == WS - 1) h1f[au] = hv;
            }
            sync_lds();
        }
    }
    // ---- fused FC on h1(TT-1): 1 row x 144 outs ----
    if (tid < ODIM) {
        float s = bfc[tid];
        const float* wr = Wfc + (size_t)tid * H;
        #pragma unroll
        for (int k = 0; k < H; ++k) s += wr[k] * h1f[k];
        out[(size_t)b * ODIM + tid] = s;
    }
}

extern "C" void kernel_launch(void* const* d_in, const int* in_sizes, int n_in,
                              void* d_out, int out_size, void* d_ws, size_t ws_size,
                              hipStream_t stream) {
    const float* x    = (const float*)d_in[0];
    const float* wih0 = (const float*)d_in[1];
    const float* whh0 = (const float*)d_in[2];
    const float* bih0 = (const float*)d_in[3];
    const float* bhh0 = (const float*)d_in[4];
    const float* wih1 = (const float*)d_in[5];
    const float* whh1 = (const float*)d_in[6];
    const float* bih1 = (const float*)d_in[7];
    const float* bhh1 = (const float*)d_in[8];
    const float* wfc  = (const float*)d_in[9];
    const float* bfc  = (const float*)d_in[10];
    float* outp = (float*)d_out;

    lstm_fused<<<BATCH, 256, 0, stream>>>(x, whh0, wih0, bih0, bhh0,
                                          wih1, whh1, bih1, bhh1,
                                          wfc, bfc, outp);
}

// Round 17
// 377.210 us; speedup vs baseline: 1.2773x; 1.2773x over previous
//
#include <hip/hip_runtime.h>
#include <hip/hip_fp16.h>
#include <cstdint>
#include <cstddef>

#define H    50
#define TT   256      // timesteps
#define BATCH 512
#define KDIM 144      // layer-0 input dim
#define ODIM 144      // FC output dim
#define NW   32       // windows
#define WS   8        // steps per window

typedef _Float16 half8  __attribute__((ext_vector_type(8)));
typedef _Float16 half4v __attribute__((ext_vector_type(4)));
typedef float    floatx4 __attribute__((ext_vector_type(4)));
typedef int      int4v  __attribute__((ext_vector_type(4)));

__device__ __forceinline__ float rcpf(float x) { return __builtin_amdgcn_rcpf(x); }
__device__ __forceinline__ float sigm(float x) { return rcpf(1.0f + __expf(-x)); }
__device__ __forceinline__ float tanhx(float x) {
    return 1.0f - 2.0f * rcpf(__expf(2.0f * x) + 1.0f);
}

// Raw barrier: orders LDS (lgkmcnt) but leaves global loads (vmcnt) in flight.
__device__ __forceinline__ void sync_lds() {
    asm volatile("s_waitcnt lgkmcnt(0)\n\ts_barrier" ::: "memory");
}
// Wave-local LDS write->read ordering (once per window after gp scatter).
__device__ __forceinline__ void wave_lds_fence() {
    asm volatile("s_waitcnt lgkmcnt(0)" ::: "memory");
}

// ---------- A-fragment builders (A layout: row m = lane&15, k = q*8 + j) ----------
// K=64 hidden rows (Whh0 / Whh1): k<50 = W[p][k], else 0.
__device__ __forceinline__ half8 make_hh(const float* __restrict__ Wt,
                                         int kkA, int gate, int q, int s) {
    const float* r0 = Wt + (size_t)(gate * H + (kkA < H ? kkA : 0)) * H;
    half8 r;
    #pragma unroll
    for (int j = 0; j < 8; ++j) {
        const int k = s * 32 + q * 8 + j;
        r[j] = (_Float16)((kkA < H && k < H) ? r0[k] : 0.0f);
    }
    return r;
}
// x-projection rows: K=160 pad; k<144 = W_ih0, k==144 = bias0 (rides 1.0 B-channel)
__device__ __forceinline__ half8 make_ax(const float* __restrict__ Wih0,
                                         const float* __restrict__ bih0,
                                         const float* __restrict__ bhh0,
                                         int kkA, int gate, int q, int s) {
    const int p = gate * H + (kkA < H ? kkA : 0);
    half8 r;
    #pragma unroll
    for (int j = 0; j < 8; ++j) {
        const int k = s * 32 + q * 8 + j;
        float v = 0.0f;
        if (kkA < H) {
            if (k < KDIM)        v = Wih0[(size_t)p * KDIM + k];
            else if (k == KDIM)  v = bih0[p] + bhh0[p];
        }
        r[j] = (_Float16)v;
    }
    return r;
}
// L1 input-projection rows (over h0 window): K=64; k<50 = W_ih1, k==50 = bias1.
__device__ __forceinline__ half8 make_p1(const float* __restrict__ Wih1,
                                         const float* __restrict__ bih1,
                                         const float* __restrict__ bhh1,
                                         int kkA, int gate, int q, int s) {
    const int p = gate * H + (kkA < H ? kkA : 0);
    half8 r;
    #pragma unroll
    for (int j = 0; j < 8; ++j) {
        const int k = s * 32 + q * 8 + j;
        float v = 0.0f;
        if (kkA < H) {
            if (k < H)           v = Wih1[(size_t)p * H + k];
            else if (k == H)     v = bih1[p] + bhh1[p];
        }
        r[j] = (_Float16)v;
    }
    return r;
}

// ---------- Kernel 0: bake the 20 per-thread x-proj frags into Acat (80 KB) ----------
// These frags are consumed once per WINDOW (not per step), so they don't need to
// live in AGPRs. Keeping them out of registers is what lets the main kernel fit
// 2 blocks/CU without spilling (R14: 44 pinned frags = 176 AGPR -> spill ->
// WRITE_SIZE 108 MB). Acat is identical for every block -> L2-broadcast reads.
__global__ __launch_bounds__(256) void wprep(const float* __restrict__ Wih0,
                                             const float* __restrict__ bih0,
                                             const float* __restrict__ bhh0,
                                             _Float16* __restrict__ Acat) {
    const int tid  = threadIdx.x;
    const int f    = blockIdx.x;     // 0..19: tl = f/5, s = f%5
    const int lane = tid & 63;
    const int w    = tid >> 6;
    const int prow = lane & 15;
    const int q    = lane >> 4;
    const int gate = prow & 3;
    const int tl   = f / 5, s = f - tl * 5;
    const int kkA  = 16 * w + 4 * tl + (prow >> 2);
    *(half8*)&Acat[(size_t)tid * 160 + f * 8] = make_ax(Wih0, bih0, bhh0, kkA, gate, q, s);
}

// ---------- Kernel 1: 1 batch row / block, 4 waves, TRUE 2 blocks/CU ----------
// 512 blocks: two independent recurrent streams per CU whose barrier phases
// interleave (phase-uncorrelated co-resident work -> fills the serial-chain
// stalls that lockstep waves cannot). Pinned AGPR set = 24 frags (96 regs):
// hh0[8] + hh1[8] + p1[8]; x-proj frags stream from Acat at window top.
__global__ __launch_bounds__(256, 2) void lstm_fused(
    const float* __restrict__ X,
    const _Float16* __restrict__ Acat,
    const float* __restrict__ Whh0,
    const float* __restrict__ Wih1, const float* __restrict__ Whh1,
    const float* __restrict__ bih1, const float* __restrict__ bhh1,
    const float* __restrict__ Wfc, const float* __restrict__ bfc,
    float* __restrict__ out)
{
    const int b    = blockIdx.x;     // batch row
    const int tid  = threadIdx.x;    // 0..255
    const int lane = tid & 63;
    const int w    = tid >> 6;       // wave 0..3
    const int col  = lane & 15;      // C col
    const int q    = lane >> 4;      // 0..3

    __shared__ __align__(16) _Float16 B1[2][2][4][8];       // h1 state [buf][s][q][j]
    __shared__ __align__(16) _Float16 HW[2][2][4][8][8];    // h0 window [buf][s][q][tok][j], 1.0@k=50
    __shared__ __align__(16) _Float16 XB[2][5][4][8][8];    // x window  [buf][s][q][tok][j], 1.0@k=144
    __shared__ __align__(16) float    gp0[64 * 36];         // L0 xproj quads [u][t*4+g]
    __shared__ __align__(16) float    gp1[64 * 36];         // L1 h0proj quads
    __shared__ float h1f[52];

    // ---- inline A-prep: 24 pinned frags (4 tiles x {hh0:2, hh1:2, p1:2}) ----
    int4v Ap[24];
    {
        const int prow = lane & 15;
        const int gate = prow & 3;
        #pragma unroll
        for (int tl = 0; tl < 4; ++tl) {
            const int kkA = 16 * w + 4 * tl + (prow >> 2);
            #pragma unroll
            for (int s = 0; s < 2; ++s) Ap[tl * 2 + s]      = __builtin_bit_cast(int4v, make_hh(Whh0, kkA, gate, q, s));
            #pragma unroll
            for (int s = 0; s < 2; ++s) Ap[8 + tl * 2 + s]  = __builtin_bit_cast(int4v, make_hh(Whh1, kkA, gate, q, s));
            #pragma unroll
            for (int s = 0; s < 2; ++s) Ap[16 + tl * 2 + s] = __builtin_bit_cast(int4v, make_p1(Wih1, bih1, bhh1, kkA, gate, q, s));
        }
    }
    #pragma unroll
    for (int i = 0; i < 24; ++i) asm volatile("" : "+a"(Ap[i]));

    const half8* axf = (const half8*)(Acat + (size_t)tid * 160);   // 20 window-top frags

    // ---- act decode: lane (col,q) owns cell (unit au, layer aL); odd cols dup ----
    const int  c2  = col >> 1;           // quad index 0..7
    const int  atl = c2 & 3;             // tile
    const int  aL  = c2 >> 2;            // layer
    const int  au  = 16 * w + 4 * atl + q;
    const bool valid = ((col & 1) == 0);
    const bool areal = (au < H);
    float c = 0.0f;
    const float* gpb = (aL ? gp1 : gp0) + au * 36;

    // ---- x-stage decode: 288 float4/window over 256 threads (+32 extra) ----
    const int cs1 = tid / 36,         kk1 = tid % 36;
    const int cs2 = (tid + 256) / 36, kk2 = (tid + 256) % 36;   // only tid<32
    const float* xq1 = X + ((size_t)b * TT + cs1) * KDIM + kk1 * 4;
    const float* xq2 = X + ((size_t)b * TT + cs2) * KDIM + kk2 * 4;

    // ---- init: zero B1/HW/XB/gp1, set 1.0 channels, stage XB[0] ----
    // XB zeroing REQUIRED: K-pad k=145..159 never written by the x-stage (R13 NaN).
    if (tid < 64) ((int*)B1)[tid] = 0;
    for (int i = tid; i < 512; i += 256) ((int*)HW)[i] = 0;
    for (int i = tid; i < 1280; i += 256) ((int*)XB)[i] = 0;
    for (int i = tid; i < 2304; i += 256) gp1[i] = 0.0f;
    __syncthreads();
    if (tid < 16) {
        HW[tid >> 3][1][2][tid & 7][2] = (_Float16)1.0f;   // k=50 bias1 channel (both bufs)
        XB[tid >> 3][4][2][tid & 7][0] = (_Float16)1.0f;   // k=144 bias0 channel (both bufs)
    }
    __syncthreads();
    {
        const float4 v1 = *(const float4*)xq1;
        half4v h; h[0]=(_Float16)v1.x; h[1]=(_Float16)v1.y; h[2]=(_Float16)v1.z; h[3]=(_Float16)v1.w;
        *(half4v*)&XB[0][kk1 >> 3][(kk1 >> 1) & 3][cs1][(kk1 & 1) * 4] = h;
        if (tid < 32) {
            const float4 v2 = *(const float4*)xq2;
            half4v h2; h2[0]=(_Float16)v2.x; h2[1]=(_Float16)v2.y; h2[2]=(_Float16)v2.z; h2[3]=(_Float16)v2.w;
            *(half4v*)&XB[0][kk2 >> 3][(kk2 >> 1) & 3][cs2][(kk2 & 1) * 4] = h2;
        }
    }
    __syncthreads();

    for (int W = 0; W < NW; ++W) {
        #pragma unroll
        for (int i = 0; i < 24; ++i) asm volatile("" : "+a"(Ap[i]));
        const int cb = W & 1, nb = cb ^ 1, pb = cb ^ 1;
        const bool more = (W + 1) < NW;
        // issue next-window x loads (consumed at step 3 -> latency hidden)
        float4 xv1, xv2;
        if (more) {
            xv1 = *(const float4*)(xq1 + (size_t)(W + 1) * WS * KDIM);
            if (tid < 32) xv2 = *(const float4*)(xq2 + (size_t)(W + 1) * WS * KDIM);
        }
        // ---- window top: L0 x-proj + bias0 (8 tokens; cols 8-15 dup) ----
        // x-frags stream from Acat (L2-broadcast; 20x16B per thread per window)
        {
            half8 xbf[5];
            #pragma unroll
            for (int s = 0; s < 5; ++s) xbf[s] = *(const half8*)&XB[cb][s][q][col & 7][0];
            #pragma unroll
            for (int tl = 0; tl < 4; ++tl) {
                floatx4 px = (floatx4)(0.0f);
                #pragma unroll
                for (int s = 0; s < 5; ++s)
                    px = __builtin_amdgcn_mfma_f32_16x16x32_f16(axf[tl * 5 + s], xbf[s], px, 0, 0, 0);
                if (col < 8)
                    *(floatx4*)&gp0[(16 * w + 4 * tl + q) * 36 + col * 4] = px;
            }
        }
        // ---- window top: L1 h0-proj + bias1 over previous window's h0 (HW[pb]) ----
        if (W > 0) {
            half8 hbf[2];
            #pragma unroll
            for (int s = 0; s < 2; ++s) hbf[s] = *(const half8*)&HW[pb][s][q][col & 7][0];
            #pragma unroll
            for (int tl = 0; tl < 4; ++tl) {
                floatx4 pw = (floatx4)(0.0f);
                #pragma unroll
                for (int s = 0; s < 2; ++s)
                    pw = __builtin_amdgcn_mfma_f32_16x16x32_f16(__builtin_bit_cast(half8, Ap[16 + tl * 2 + s]), hbf[s], pw, 0, 0, 0);
                if (col < 8)
                    *(floatx4*)&gp1[(16 * w + 4 * tl + q) * 36 + col * 4] = pw;
            }
        }
        wave_lds_fence();   // gp scatter -> same-wave act reads
        // ---- 8 serial steps: L0 at t=8W+i, L1 at t'=8(W-1)+i ----
        #pragma unroll
        for (int i = 0; i < WS; ++i) {
            const int rb = i & 1, wb = rb ^ 1;
            const int b0i = (i == 0) ? pb : cb;        // h0(t-1) lives in HW
            const int tprev = (i == 0) ? 7 : (i - 1);
            half8 bf0[2], bf1[2];
            #pragma unroll
            for (int s = 0; s < 2; ++s) {
                bf0[s] = *(const half8*)&HW[b0i][s][q][tprev][0];   // broadcast
                bf1[s] = *(const half8*)&B1[rb][s][q][0];           // broadcast
            }
            const floatx4 gx = *(const floatx4*)&gpb[i * 4];
            floatx4 a0[4], a1[4];
            #pragma unroll
            for (int tl = 0; tl < 4; ++tl) { a0[tl] = (floatx4)(0.0f); a1[tl] = (floatx4)(0.0f); }
            #pragma unroll
            for (int tl = 0; tl < 4; ++tl) {
                #pragma unroll
                for (int s = 0; s < 2; ++s) {
                    a0[tl] = __builtin_amdgcn_mfma_f32_16x16x32_f16(__builtin_bit_cast(half8, Ap[tl*2+s]),   bf0[s], a0[tl], 0, 0, 0);
                    a1[tl] = __builtin_amdgcn_mfma_f32_16x16x32_f16(__builtin_bit_cast(half8, Ap[8+tl*2+s]), bf1[s], a1[tl], 0, 0, 0);
                }
            }
            // ---- in-register 8-way quad select (28 cndmask) ----
            floatx4 g;
            #pragma unroll
            for (int gi_ = 0; gi_ < 4; ++gi_) {
                const float s01a = (c2 & 1) ? a0[1][gi_] : a0[0][gi_];
                const float s23a = (c2 & 1) ? a0[3][gi_] : a0[2][gi_];
                const float s01b = (c2 & 1) ? a1[1][gi_] : a1[0][gi_];
                const float s23b = (c2 & 1) ? a1[3][gi_] : a1[2][gi_];
                const float e0 = (c2 & 2) ? s23a : s01a;
                const float e1 = (c2 & 2) ? s23b : s01b;
                g[gi_] = (c2 & 4) ? e1 : e0;
            }
            g[0] += gx[0]; g[1] += gx[1]; g[2] += gx[2]; g[3] += gx[3];
            // ---- act: one cell per lane (L1 lags a window: dead at W==0) ----
            const float gi = sigm(g[0]), gf = sigm(g[1]);
            const float gg = tanhx(g[2]), go = sigm(g[3]);
            const bool en = (aL == 0) || (W > 0);
            const float cn = gf * c + gi * gg;
            c = en ? cn : c;
            const float hv = go * tanhx(c);
            if (valid && areal && en) {
                const _Float16 h16 = (_Float16)hv;
                if (aL == 0)
                    HW[cb][au >> 5][(au >> 3) & 3][i][au & 7] = h16;
                else
                    B1[wb][au >> 5][(au >> 3) & 3][au & 7] = h16;
            }
            // mid-window: write next-window x into XB[nb] (loads long in flight)
            if (i == 3 && more) {
                half4v h; h[0]=(_Float16)xv1.x; h[1]=(_Float16)xv1.y; h[2]=(_Float16)xv1.z; h[3]=(_Float16)xv1.w;
                *(half4v*)&XB[nb][kk1 >> 3][(kk1 >> 1) & 3][cs1][(kk1 & 1) * 4] = h;
                if (tid < 32) {
                    half4v h2; h2[0]=(_Float16)xv2.x; h2[1]=(_Float16)xv2.y; h2[2]=(_Float16)xv2.z; h2[3]=(_Float16)xv2.w;
                    *(half4v*)&XB[nb][kk2 >> 3][(kk2 >> 1) & 3][cs2][(kk2 & 1) * 4] = h2;
                }
            }
            sync_lds();         // HW[cb]/B1[wb]/XB[nb] -> next step
        }
    }
    // ---- tail window: L1 for t' = TT-8 .. TT-1 (h0 from HW[(NW-1)&1]) ----
    {
        #pragma unroll
        for (int i = 0; i < 24; ++i) asm volatile("" : "+a"(Ap[i]));
        {
            half8 hbf[2];
            #pragma unroll
            for (int s = 0; s < 2; ++s) hbf[s] = *(const half8*)&HW[(NW - 1) & 1][s][q][col & 7][0];
            #pragma unroll
            for (int tl = 0; tl < 4; ++tl) {
                floatx4 pw = (floatx4)(0.0f);
                #pragma unroll
                for (int s = 0; s < 2; ++s)
                    pw = __builtin_amdgcn_mfma_f32_16x16x32_f16(__builtin_bit_cast(half8, Ap[16 + tl * 2 + s]), hbf[s], pw, 0, 0, 0);
                if (col < 8)
                    *(floatx4*)&gp1[(16 * w + 4 * tl + q) * 36 + col * 4] = pw;
            }
        }
        wave_lds_fence();
        #pragma unroll
        for (int i = 0; i < WS; ++i) {
            const int rb = i & 1, wb = rb ^ 1;
            half8 bf1[2];
            #pragma unroll
            for (int s = 0; s < 2; ++s) bf1[s] = *(const half8*)&B1[rb][s][q][0];
            const floatx4 gx = *(const floatx4*)&gpb[i * 4];
            floatx4 a1[4];
            #pragma unroll
            for (int tl = 0; tl < 4; ++tl) {
                a1[tl] = (floatx4)(0.0f);
                #pragma unroll
                for (int s = 0; s < 2; ++s)
                    a1[tl] = __builtin_amdgcn_mfma_f32_16x16x32_f16(__builtin_bit_cast(half8, Ap[8+tl*2+s]), bf1[s], a1[tl], 0, 0, 0);
            }
            floatx4 g;
            #pragma unroll
            for (int gi_ = 0; gi_ < 4; ++gi_) {
                const float s01 = (c2 & 1) ? a1[1][gi_] : a1[0][gi_];
                const float s23 = (c2 & 1) ? a1[3][gi_] : a1[2][gi_];
                g[gi_] = (c2 & 2) ? s23 : s01;
            }
            g[0] += gx[0]; g[1] += gx[1]; g[2] += gx[2]; g[3] += gx[3];
            const float gi = sigm(g[0]), gf = sigm(g[1]);
            const float gg = tanhx(g[2]), go = sigm(g[3]);
            const bool en = (aL == 1);
            const float cn = gf * c + gi * gg;
            c = en ? cn : c;
            const float hv = go * tanhx(c);
            if (valid && en && areal) {
                B1[wb][au >> 5][(au >> 3) & 3][au & 7] = (_Float16)hv;
                if (i == WS - 1) h1f[au] = hv;
            }
            sync_lds();
        }
    }
    // ---- fused FC on h1(TT-1): 1 row x 144 outs ----
    if (tid < ODIM) {
        float s = bfc[tid];
        const float* wr = Wfc + (size_t)tid * H;
        #pragma unroll
        for (int k = 0; k < H; ++k) s += wr[k] * h1f[k];
        out[(size_t)b * ODIM + tid] = s;
    }
}

extern "C" void kernel_launch(void* const* d_in, const int* in_sizes, int n_in,
                              void* d_out, int out_size, void* d_ws, size_t ws_size,
                              hipStream_t stream) {
    const float* x    = (const float*)d_in[0];
    const float* wih0 = (const float*)d_in[1];
    const float* whh0 = (const float*)d_in[2];
    const float* bih0 = (const float*)d_in[3];
    const float* bhh0 = (const float*)d_in[4];
    const float* wih1 = (const float*)d_in[5];
    const float* whh1 = (const float*)d_in[6];
    const float* bih1 = (const float*)d_in[7];
    const float* bhh1 = (const float*)d_in[8];
    const float* wfc  = (const float*)d_in[9];
    const float* bfc  = (const float*)d_in[10];
    float* outp = (float*)d_out;

    _Float16* Acat = (_Float16*)d_ws;   // 256 threads x 160 halfs = 81,920 B

    wprep<<<20, 256, 0, stream>>>(wih0, bih0, bhh0, Acat);
    lstm_fused<<<BATCH, 256, 0, stream>>>(x, Acat, whh0,
                                          wih1, whh1, bih1, bhh1,
                                          wfc, bfc, outp);
}